// Round 1
// baseline (2838.501 us; speedup 1.0000x reference)
//
#include <hip/hip_runtime.h>

#define N0 100000
#define N1 50000
#define N2 25000
#define E0 500000
#define E1 250000

static __device__ __forceinline__ float lrelu(float x, float s) {
    return x >= 0.f ? x : s * x;
}

// ---------------- GEMM: Y = act(X @ W + b), K = Ncols = 128 ----------------
// X rows contiguous (stride 128). Y row stride ldy. slope<0 => no activation.
__global__ __launch_bounds__(256) void gemm128(
    const float* __restrict__ X,
    const float* __restrict__ W,
    const float* __restrict__ bias,
    float* __restrict__ Y, int ldy,
    int M, float slope)
{
    __shared__ float xs[32][128];
    const int row0 = blockIdx.x * 32;
    const int tid = threadIdx.x;
    for (int i = tid; i < 32 * 32; i += 256) {
        int r = i >> 5, c4 = i & 31;
        float4 v = make_float4(0.f, 0.f, 0.f, 0.f);
        if (row0 + r < M) v = ((const float4*)(X + (size_t)(row0 + r) * 128))[c4];
        ((float4*)&xs[r][0])[c4] = v;
    }
    __syncthreads();
    const int row_t = tid >> 5;   // 0..7 -> rows row_t*4 .. +3
    const int col_t = tid & 31;   // cols col_t*4 .. +3
    float acc[4][4] = {};
    #pragma unroll 4
    for (int k4 = 0; k4 < 32; ++k4) {
        const float4* Wp = (const float4*)(W + (size_t)k4 * 4 * 128);
        float4 w0 = Wp[col_t];
        float4 w1 = Wp[32 + col_t];
        float4 w2 = Wp[64 + col_t];
        float4 w3 = Wp[96 + col_t];
        #pragma unroll
        for (int r = 0; r < 4; ++r) {
            float4 xv = ((const float4*)&xs[row_t * 4 + r][0])[k4];
            acc[r][0] += xv.x * w0.x + xv.y * w1.x + xv.z * w2.x + xv.w * w3.x;
            acc[r][1] += xv.x * w0.y + xv.y * w1.y + xv.z * w2.y + xv.w * w3.y;
            acc[r][2] += xv.x * w0.z + xv.y * w1.z + xv.z * w2.z + xv.w * w3.z;
            acc[r][3] += xv.x * w0.w + xv.y * w1.w + xv.z * w2.w + xv.w * w3.w;
        }
    }
    #pragma unroll
    for (int r = 0; r < 4; ++r) {
        int row = row0 + row_t * 4 + r;
        if (row >= M) continue;
        float4 o;
        float* op = (float*)&o;
        #pragma unroll
        for (int c = 0; c < 4; ++c) {
            float vv = acc[r][c];
            if (bias) vv += bias[col_t * 4 + c];
            if (slope >= 0.f) vv = lrelu(vv, slope);
            op[c] = vv;
        }
        *((float4*)(Y + (size_t)row * ldy + col_t * 4)) = o;
    }
}

// ---------------- el/er: per-node per-head attention logit halves ----------
__global__ __launch_bounds__(256) void elr_kernel(
    const float* __restrict__ P, const float* __restrict__ al, const float* __restrict__ ar,
    float* __restrict__ el, float* __restrict__ er, int n)
{
    int idx = blockIdx.x * 256 + threadIdx.x;
    int node = idx >> 7;
    int l = idx & 127;
    if (node >= n) return;
    float h = P[(size_t)node * 128 + l];
    float pl = h * al[l];
    float pr = h * ar[l];
    #pragma unroll
    for (int m = 1; m < 32; m <<= 1) {
        pl += __shfl_xor(pl, m);
        pr += __shfl_xor(pr, m);
    }
    if ((l & 31) == 0) {
        el[(size_t)node * 4 + (l >> 5)] = pl;
        er[(size_t)node * 4 + (l >> 5)] = pr;
    }
}

// ---------------- per-edge pre-softmax logits ----------------
__global__ __launch_bounds__(256) void edge_e_kernel(
    const int* __restrict__ src, const int* __restrict__ dst,
    const float* __restrict__ el, const float* __restrict__ er,
    float* __restrict__ eb, int E)
{
    int e = blockIdx.x * 256 + threadIdx.x;
    if (e >= E) return;
    float4 a = ((const float4*)el)[src[e]];
    float4 b = ((const float4*)er)[dst[e]];
    float4 r;
    r.x = lrelu(a.x + b.x, 0.2f);
    r.y = lrelu(a.y + b.y, 0.2f);
    r.z = lrelu(a.z + b.z, 0.2f);
    r.w = lrelu(a.w + b.w, 0.2f);
    ((float4*)eb)[e] = r;
}

// ---------------- CSR build ----------------
__global__ __launch_bounds__(256) void count_kernel(
    const int* __restrict__ dst, int* __restrict__ counts, int E)
{
    int e = blockIdx.x * 256 + threadIdx.x;
    if (e < E) atomicAdd(&counts[dst[e]], 1);
}

__global__ __launch_bounds__(1024) void scan_block_kernel(
    const int* __restrict__ counts, int* __restrict__ incl, int* __restrict__ bsum, int n)
{
    __shared__ int s[1024];
    int i = blockIdx.x * 1024 + threadIdx.x;
    int v = (i < n) ? counts[i] : 0;
    s[threadIdx.x] = v;
    __syncthreads();
    for (int off = 1; off < 1024; off <<= 1) {
        int t = (threadIdx.x >= off) ? s[threadIdx.x - off] : 0;
        __syncthreads();
        s[threadIdx.x] += t;
        __syncthreads();
    }
    if (i < n) incl[i] = s[threadIdx.x];
    if (threadIdx.x == 1023) bsum[blockIdx.x] = s[1023];
}

__global__ void scan_bsum_kernel(int* bsum, int nb)
{
    if (blockIdx.x == 0 && threadIdx.x == 0) {
        int acc = 0;
        for (int i = 0; i < nb; ++i) { int t = bsum[i]; bsum[i] = acc; acc += t; }
        bsum[nb] = acc;
    }
}

__global__ __launch_bounds__(256) void scan_final_kernel(
    const int* __restrict__ counts, const int* __restrict__ incl,
    const int* __restrict__ bsum, int* __restrict__ offs, int* __restrict__ cursor,
    int n, int nb)
{
    int i = blockIdx.x * 256 + threadIdx.x;
    if (i < n) {
        int ex = incl[i] - counts[i] + bsum[i >> 10];
        offs[i] = ex;
        cursor[i] = ex;
    }
    if (i == 0) offs[n] = bsum[nb];
}

__global__ __launch_bounds__(256) void scatter_kernel(
    const int* __restrict__ dst, int* __restrict__ cursor, int* __restrict__ csr, int E)
{
    int e = blockIdx.x * 256 + threadIdx.x;
    if (e < E) {
        int p = atomicAdd(&cursor[dst[e]], 1);
        csr[p] = e;
    }
}

// ---------------- per-dst-node softmax + weighted gather ----------------
// block = 128 threads, one block per destination node. tid -> (g = tid>>5, d = tid&31)
__global__ __launch_bounds__(128) void gat_gather(
    const int* __restrict__ src, const int* __restrict__ csr,
    const int* __restrict__ offs, const float* __restrict__ eb,
    const float* __restrict__ P, float* __restrict__ out, int ldo, int n)
{
    int node = blockIdx.x;
    int tid = threadIdx.x;
    int g = tid >> 5;
    int beg = offs[node], end = offs[node + 1];
    float m = -1e30f;
    for (int i = beg; i < end; ++i)
        m = fmaxf(m, eb[(size_t)csr[i] * 4 + g]);
    float den = 0.f, acc = 0.f;
    for (int i = beg; i < end; ++i) {
        int e = csr[i];
        float w = __expf(eb[(size_t)e * 4 + g] - m);
        den += w;
        acc += w * P[(size_t)src[e] * 128 + tid];
    }
    float r = (end > beg) ? acc / den : 0.f;
    out[(size_t)node * ldo + tid] = lrelu(r, 0.01f);
}

// ---------------- gated attention combine ----------------
// tid&127 -> (a = t>>4, h = t&15); e-reduction over 16 lanes; softmax over K in regs.
template <int K>
__global__ __launch_bounds__(256) void attn_combine(
    const float* __restrict__ gl, const float* __restrict__ gr,
    const float* __restrict__ v, const float* __restrict__ aW,
    int n,
    float* __restrict__ out1, int ld1,
    float* __restrict__ out2, int ld2, int n2)
{
    int node = blockIdx.x * 2 + (threadIdx.x >> 7);
    int tid = threadIdx.x & 127;
    if (node >= n) return;
    float aw = aW[tid & 15];
    float glv = gl[(size_t)node * 128 + tid];
    float e[K];
    #pragma unroll
    for (int k = 0; k < K; ++k) {
        float z = lrelu(glv + gr[((size_t)node * K + k) * 128 + tid], 0.01f);
        float p = z * aw;
        p += __shfl_xor(p, 1);
        p += __shfl_xor(p, 2);
        p += __shfl_xor(p, 4);
        p += __shfl_xor(p, 8);
        e[k] = p;
    }
    float m = e[0];
    #pragma unroll
    for (int k = 1; k < K; ++k) m = fmaxf(m, e[k]);
    float s = 0.f, w[K];
    #pragma unroll
    for (int k = 0; k < K; ++k) { w[k] = __expf(e[k] - m); s += w[k]; }
    float inv = 1.f / s;
    float acc = 0.f;
    #pragma unroll
    for (int k = 0; k < K; ++k)
        acc += (w[k] * inv) * v[((size_t)node * K + k) * 128 + tid];
    float r = lrelu(acc, 0.01f);
    out1[(size_t)node * ld1 + tid] = r;
    if (out2 && node < n2) out2[(size_t)node * ld2 + tid] = r;
}

// ---------------- final linear 128 -> 2 ----------------
__global__ __launch_bounds__(256) void lin_kernel(
    const float* __restrict__ H, const float* __restrict__ W,
    const float* __restrict__ b, float* __restrict__ out, int n)
{
    int idx = blockIdx.x * 256 + threadIdx.x;
    int node = idx >> 1, c = idx & 1;
    if (node >= n) return;
    float acc = 0.f;
    for (int k = 0; k < 128; ++k)
        acc += H[(size_t)node * 128 + k] * W[k * 2 + c];
    out[(size_t)node * 2 + c] = acc + b[c];
}

extern "C" void kernel_launch(void* const* d_in, const int* in_sizes, int n_in,
                              void* d_out, int out_size, void* d_ws, size_t ws_size,
                              hipStream_t stream)
{
    (void)in_sizes; (void)n_in; (void)out_size;
    const float* x       = (const float*)d_in[0];
    const int*   src0    = (const int*)d_in[1];
    const int*   dst0    = (const int*)d_in[2];
    const int*   src1    = (const int*)d_in[3];
    const int*   dst1    = (const int*)d_in[4];
    const float* conv_W  = (const float*)d_in[5];
    const float* conv_al = (const float*)d_in[6];
    const float* conv_ar = (const float*)d_in[7];
    const float* feat_W  = (const float*)d_in[8];
    const float* feat_b  = (const float*)d_in[9];
    const float* relWl_W = (const float*)d_in[10];
    const float* relWl_b = (const float*)d_in[11];
    const float* relWr_W = (const float*)d_in[12];
    const float* relWr_b = (const float*)d_in[13];
    const float* relP_W  = (const float*)d_in[14];
    const float* relP_b  = (const float*)d_in[15];
    const float* rela_W  = (const float*)d_in[16];
    /* d_in[17] rela_b: additive constant over k -> softmax-invariant, skipped */
    const float* proj_W  = (const float*)d_in[18];
    const float* proj_b  = (const float*)d_in[19];
    const float* hopWl_W = (const float*)d_in[20];
    const float* hopWl_b = (const float*)d_in[21];
    const float* hopWr_W = (const float*)d_in[22];
    const float* hopWr_b = (const float*)d_in[23];
    const float* hopP_W  = (const float*)d_in[24];
    const float* hopP_b  = (const float*)d_in[25];
    const float* hopa_W  = (const float*)d_in[26];
    /* d_in[27] hopa_b: softmax-invariant, skipped */
    const float* lin_W   = (const float*)d_in[28];
    const float* lin_b   = (const float*)d_in[29];
    float* out = (float*)d_out;

    // ---- bump allocator over d_ws ----
    char* base = (char*)d_ws;
    size_t off = 0;
    auto alloc = [&](size_t bytes) -> void* {
        void* p = base + off;
        off += (bytes + 255) & ~(size_t)255;
        return p;
    };
    float* hopstack = (float*)alloc((size_t)N2 * 384 * 4);   // (25000, 3, 128)
    float* F        = (float*)alloc((size_t)N1 * 512 * 4);   // stacked feats (n, 4, 128)
    float* P        = (float*)alloc((size_t)N0 * 128 * 4);   // conv projection
    float* el       = (float*)alloc((size_t)N0 * 4 * 4);
    float* er       = (float*)alloc((size_t)N0 * 4 * 4);
    float* eb       = (float*)alloc((size_t)E0 * 4 * 4);     // per-edge 4-head logits
    int*   csr      = (int*)alloc((size_t)E0 * 4);
    int*   counts   = (int*)alloc((size_t)N1 * 4);
    int*   incl     = (int*)alloc((size_t)N1 * 4);
    int*   offs     = (int*)alloc((size_t)(N1 + 1) * 4);
    int*   cursor   = (int*)alloc((size_t)N1 * 4);
    int*   bsum     = (int*)alloc(256 * 4);
    float* glbuf    = (float*)alloc((size_t)N1 * 128 * 4);
    float* h1       = (float*)alloc((size_t)N1 * 128 * 4);
    size_t rem = ws_size > off ? ws_size - off : 0;
    int CHUNK = (int)(rem / (2ull * 512 * 4 + 1));
    if (CHUNK > 16384) CHUNK = 16384;
    if (CHUNK < 256) CHUNK = 256;
    float* grbuf = (float*)alloc((size_t)CHUNK * 512 * 4);
    float* vbuf  = (float*)alloc((size_t)CHUNK * 512 * 4);
    float* hout  = P;  // P is dead by the hop stage

    // ---- one GAT conv rep: project, logits, CSR, softmax-gather ----
    auto run_conv = [&](const float* h, int n_src, int n_dst,
                        const int* srcJ, const int* dstJ, int E,
                        const float* Wc, const float* al, const float* ar,
                        float* outF) {
        gemm128<<<(n_src + 31) / 32, 256, 0, stream>>>(h, Wc, nullptr, P, 128, n_src, -1.f);
        elr_kernel<<<((unsigned)n_src * 128 + 255) / 256, 256, 0, stream>>>(P, al, ar, el, er, n_src);
        hipMemsetAsync(counts, 0, (size_t)n_dst * sizeof(int), stream);
        count_kernel<<<(E + 255) / 256, 256, 0, stream>>>(dstJ, counts, E);
        int nb = (n_dst + 1023) / 1024;
        scan_block_kernel<<<nb, 1024, 0, stream>>>(counts, incl, bsum, n_dst);
        scan_bsum_kernel<<<1, 64, 0, stream>>>(bsum, nb);
        scan_final_kernel<<<(n_dst + 255) / 256, 256, 0, stream>>>(counts, incl, bsum, offs, cursor, n_dst, nb);
        scatter_kernel<<<(E + 255) / 256, 256, 0, stream>>>(dstJ, cursor, csr, E);
        edge_e_kernel<<<(E + 255) / 256, 256, 0, stream>>>(srcJ, dstJ, el, er, eb, E);
        gat_gather<<<n_dst, 128, 0, stream>>>(srcJ, csr, offs, eb, P, outF, 512, n_dst);
    };

    // ---- one gated attention: gl/gr/v GEMMs (gr/v chunked) + combine ----
    auto run_attn = [&](const float* prev, const float* feats, int n, int K,
                        const float* Wl, const float* bl,
                        const float* Wr, const float* br,
                        const float* Wp, const float* bp,
                        const float* aW,
                        float* out1, int ld1, float* out2, int ld2, int n2) {
        gemm128<<<(n + 31) / 32, 256, 0, stream>>>(prev, Wl, bl, glbuf, 128, n, -1.f);
        for (int c = 0; c < n; c += CHUNK) {
            int mn = (n - c < CHUNK) ? (n - c) : CHUNK;
            int rows = mn * K;
            const float* Xf = feats + (size_t)c * K * 128;
            gemm128<<<(rows + 31) / 32, 256, 0, stream>>>(Xf, Wr, br, grbuf, 128, rows, -1.f);
            gemm128<<<(rows + 31) / 32, 256, 0, stream>>>(Xf, Wp, bp, vbuf, 128, rows, -1.f);
            float* o2 = nullptr;
            int o2n = 0;
            if (out2 && c < n2) {
                o2 = out2 + (size_t)c * ld2;
                o2n = ((n2 - c) < mn) ? (n2 - c) : mn;
            }
            if (K == 4)
                attn_combine<4><<<(mn + 1) / 2, 256, 0, stream>>>(
                    glbuf + (size_t)c * 128, grbuf, vbuf, aW, mn,
                    out1 + (size_t)c * ld1, ld1, o2, ld2, o2n);
            else
                attn_combine<3><<<(mn + 1) / 2, 256, 0, stream>>>(
                    glbuf + (size_t)c * 128, grbuf, vbuf, aW, mn,
                    out1 + (size_t)c * ld1, ld1, o2, ld2, o2n);
        }
    };

    // ---- layer_features[0] = x[:N2] @ proj_W + proj_b (no act) ----
    gemm128<<<(N2 + 31) / 32, 256, 0, stream>>>(x, proj_W, proj_b, hopstack, 384, N2, -1.f);

    // ---- layer 0 ----
    for (int j = 0; j < 3; ++j)
        run_conv(x, N0, N1, src0 + (size_t)j * E0, dst0 + (size_t)j * E0, E0,
                 conv_W + (size_t)j * 16384, conv_al + (size_t)j * 128, conv_ar + (size_t)j * 128,
                 F + j * 128);
    gemm128<<<(N1 + 31) / 32, 256, 0, stream>>>(x, feat_W, feat_b, F + 3 * 128, 512, N1, 0.01f);
    run_attn(x, F, N1, 4,
             relWl_W, relWl_b, relWr_W, relWr_b, relP_W, relP_b, rela_W,
             h1, 128, hopstack + 128, 384, N2);

    // ---- layer 1 ----
    for (int j = 0; j < 3; ++j)
        run_conv(h1, N1, N2, src1 + (size_t)j * E1, dst1 + (size_t)j * E1, E1,
                 conv_W + (size_t)(3 + j) * 16384, conv_al + (size_t)(3 + j) * 128,
                 conv_ar + (size_t)(3 + j) * 128, F + j * 128);
    gemm128<<<(N2 + 31) / 32, 256, 0, stream>>>(h1, feat_W + 16384, feat_b + 128, F + 3 * 128, 512, N2, 0.01f);
    run_attn(h1, F, N2, 4,
             relWl_W + 16384, relWl_b + 128, relWr_W + 16384, relWr_b + 128,
             relP_W + 16384, relP_b + 128, rela_W + 16,
             hopstack + 2 * 128, 384, nullptr, 0, 0);

    // ---- hop attention over [proj, h1[:N2], h2] ----
    run_attn(x, hopstack, N2, 3,
             hopWl_W, hopWl_b, hopWr_W, hopWr_b, hopP_W, hopP_b, hopa_W,
             hout, 128, nullptr, 0, 0);

    // ---- final linear ----
    lin_kernel<<<(N2 * 2 + 255) / 256, 256, 0, stream>>>(hout, lin_W, lin_b, out, N2);
}

// Round 2
// 2208.112 us; speedup vs baseline: 1.2855x; 1.2855x over previous
//
#include <hip/hip_runtime.h>

#define N0 100000
#define N1 50000
#define N2 25000
#define E0 500000
#define E1 250000

static __device__ __forceinline__ float lrelu(float x, float s) {
    return x >= 0.f ? x : s * x;
}

// ---------------- GEMM: Y = act(X @ W + b), K = Ncols = 128 ----------------
__global__ __launch_bounds__(256) void gemm128(
    const float* __restrict__ X,
    const float* __restrict__ W,
    const float* __restrict__ bias,
    float* __restrict__ Y, int ldy,
    int M, float slope)
{
    __shared__ float xs[32][128];
    const int row0 = blockIdx.x * 32;
    const int tid = threadIdx.x;
    for (int i = tid; i < 32 * 32; i += 256) {
        int r = i >> 5, c4 = i & 31;
        float4 v = make_float4(0.f, 0.f, 0.f, 0.f);
        if (row0 + r < M) v = ((const float4*)(X + (size_t)(row0 + r) * 128))[c4];
        ((float4*)&xs[r][0])[c4] = v;
    }
    __syncthreads();
    const int row_t = tid >> 5;
    const int col_t = tid & 31;
    float acc[4][4] = {};
    #pragma unroll 4
    for (int k4 = 0; k4 < 32; ++k4) {
        const float4* Wp = (const float4*)(W + (size_t)k4 * 4 * 128);
        float4 w0 = Wp[col_t];
        float4 w1 = Wp[32 + col_t];
        float4 w2 = Wp[64 + col_t];
        float4 w3 = Wp[96 + col_t];
        #pragma unroll
        for (int r = 0; r < 4; ++r) {
            float4 xv = ((const float4*)&xs[row_t * 4 + r][0])[k4];
            acc[r][0] += xv.x * w0.x + xv.y * w1.x + xv.z * w2.x + xv.w * w3.x;
            acc[r][1] += xv.x * w0.y + xv.y * w1.y + xv.z * w2.y + xv.w * w3.y;
            acc[r][2] += xv.x * w0.z + xv.y * w1.z + xv.z * w2.z + xv.w * w3.z;
            acc[r][3] += xv.x * w0.w + xv.y * w1.w + xv.z * w2.w + xv.w * w3.w;
        }
    }
    #pragma unroll
    for (int r = 0; r < 4; ++r) {
        int row = row0 + row_t * 4 + r;
        if (row >= M) continue;
        float4 o;
        float* op = (float*)&o;
        #pragma unroll
        for (int c = 0; c < 4; ++c) {
            float vv = acc[r][c];
            if (bias) vv += bias[col_t * 4 + c];
            if (slope >= 0.f) vv = lrelu(vv, slope);
            op[c] = vv;
        }
        *((float4*)(Y + (size_t)row * ldy + col_t * 4)) = o;
    }
}

// ---------------- el/er ----------------
__global__ __launch_bounds__(256) void elr_kernel(
    const float* __restrict__ P, const float* __restrict__ al, const float* __restrict__ ar,
    float* __restrict__ el, float* __restrict__ er, int n)
{
    int idx = blockIdx.x * 256 + threadIdx.x;
    int node = idx >> 7;
    int l = idx & 127;
    if (node >= n) return;
    float h = P[(size_t)node * 128 + l];
    float pl = h * al[l];
    float pr = h * ar[l];
    #pragma unroll
    for (int m = 1; m < 32; m <<= 1) {
        pl += __shfl_xor(pl, m);
        pr += __shfl_xor(pr, m);
    }
    if ((l & 31) == 0) {
        el[(size_t)node * 4 + (l >> 5)] = pl;
        er[(size_t)node * 4 + (l >> 5)] = pr;
    }
}

// ---------------- per-edge pre-softmax logits ----------------
__global__ __launch_bounds__(256) void edge_e_kernel(
    const int* __restrict__ src, const int* __restrict__ dst,
    const float* __restrict__ el, const float* __restrict__ er,
    float* __restrict__ eb, int E)
{
    int e = blockIdx.x * 256 + threadIdx.x;
    if (e >= E) return;
    float4 a = ((const float4*)el)[src[e]];
    float4 b = ((const float4*)er)[dst[e]];
    float4 r;
    r.x = lrelu(a.x + b.x, 0.2f);
    r.y = lrelu(a.y + b.y, 0.2f);
    r.z = lrelu(a.z + b.z, 0.2f);
    r.w = lrelu(a.w + b.w, 0.2f);
    ((float4*)eb)[e] = r;
}

// ---------------- CSR build ----------------
__global__ __launch_bounds__(256) void count_kernel(
    const int* __restrict__ dst, int* __restrict__ counts, int E)
{
    int e = blockIdx.x * 256 + threadIdx.x;
    if (e < E) atomicAdd(&counts[dst[e]], 1);
}

__global__ __launch_bounds__(1024) void scan_block_kernel(
    const int* __restrict__ counts, int* __restrict__ incl, int* __restrict__ bsum, int n)
{
    __shared__ int s[1024];
    int i = blockIdx.x * 1024 + threadIdx.x;
    int v = (i < n) ? counts[i] : 0;
    s[threadIdx.x] = v;
    __syncthreads();
    for (int off = 1; off < 1024; off <<= 1) {
        int t = (threadIdx.x >= off) ? s[threadIdx.x - off] : 0;
        __syncthreads();
        s[threadIdx.x] += t;
        __syncthreads();
    }
    if (i < n) incl[i] = s[threadIdx.x];
    if (threadIdx.x == 1023) bsum[blockIdx.x] = s[1023];
}

__global__ void scan_bsum_kernel(int* bsum, int nb)
{
    if (blockIdx.x == 0 && threadIdx.x == 0) {
        int acc = 0;
        for (int i = 0; i < nb; ++i) { int t = bsum[i]; bsum[i] = acc; acc += t; }
        bsum[nb] = acc;
    }
}

__global__ __launch_bounds__(256) void scan_final_kernel(
    const int* __restrict__ counts, const int* __restrict__ incl,
    const int* __restrict__ bsum, int* __restrict__ offs, int* __restrict__ cursor,
    int n, int nb)
{
    int i = blockIdx.x * 256 + threadIdx.x;
    if (i < n) {
        int ex = incl[i] - counts[i] + bsum[i >> 10];
        offs[i] = ex;
        cursor[i] = ex;
    }
    if (i == 0) offs[n] = bsum[nb];
}

__global__ __launch_bounds__(256) void scatter_kernel(
    const int* __restrict__ dst, int* __restrict__ cursor, int* __restrict__ csr, int E)
{
    int e = blockIdx.x * 256 + threadIdx.x;
    if (e < E) {
        int p = atomicAdd(&cursor[dst[e]], 1);
        csr[p] = e;
    }
}

// ---------------- per-dst-node softmax + weighted gather (slot-parallel) ----
// 256 threads: slot = t>>5 (8 edge slots in flight), lane = t&31 (float4 cols),
// head g = lane>>3. Two passes + LDS tree reduce.
__global__ __launch_bounds__(256) void gat_gather2(
    const int* __restrict__ src, const int* __restrict__ csr,
    const int* __restrict__ offs, const float* __restrict__ eb,
    const float* __restrict__ P, float* __restrict__ out, int ldo, int n)
{
    __shared__ float4 accs[8][32];
    __shared__ float reds[8][32];
    int node = blockIdx.x;
    int t = threadIdx.x;
    int lane = t & 31;
    int slot = t >> 5;
    int g = lane >> 3;
    int beg = offs[node], end = offs[node + 1];
    // pass 1: per-head max (slot-parallel)
    float m = -1e30f;
    for (int i = beg + slot; i < end; i += 8)
        m = fmaxf(m, eb[(size_t)csr[i] * 4 + g]);
    reds[slot][lane] = m;
    __syncthreads();
    if (slot < 4) reds[slot][lane] = fmaxf(reds[slot][lane], reds[slot + 4][lane]);
    __syncthreads();
    if (slot < 2) reds[slot][lane] = fmaxf(reds[slot][lane], reds[slot + 2][lane]);
    __syncthreads();
    m = fmaxf(reds[0][lane], reds[1][lane]);
    // pass 2: exp-weights + gathered accumulation (8 rows in flight per block)
    float den = 0.f;
    float4 acc = make_float4(0.f, 0.f, 0.f, 0.f);
    for (int i = beg + slot; i < end; i += 8) {
        int e = csr[i];
        float w = __expf(eb[(size_t)e * 4 + g] - m);
        den += w;
        float4 p = ((const float4*)(P + (size_t)src[e] * 128))[lane];
        acc.x += w * p.x; acc.y += w * p.y; acc.z += w * p.z; acc.w += w * p.w;
    }
    __syncthreads();  // everyone done reading reds (for m) before overwrite
    reds[slot][lane] = den;
    accs[slot][lane] = acc;
    __syncthreads();
    if (slot < 4) {
        reds[slot][lane] += reds[slot + 4][lane];
        float4 b = accs[slot + 4][lane];
        accs[slot][lane].x += b.x; accs[slot][lane].y += b.y;
        accs[slot][lane].z += b.z; accs[slot][lane].w += b.w;
    }
    __syncthreads();
    if (slot < 2) {
        reds[slot][lane] += reds[slot + 2][lane];
        float4 b = accs[slot + 2][lane];
        accs[slot][lane].x += b.x; accs[slot][lane].y += b.y;
        accs[slot][lane].z += b.z; accs[slot][lane].w += b.w;
    }
    __syncthreads();
    if (slot == 0) {
        float d = reds[0][lane] + reds[1][lane];
        float4 a0 = accs[0][lane], a1 = accs[1][lane];
        float inv = (end > beg) ? 1.f / d : 0.f;
        float4 o;
        o.x = lrelu((a0.x + a1.x) * inv, 0.01f);
        o.y = lrelu((a0.y + a1.y) * inv, 0.01f);
        o.z = lrelu((a0.z + a1.z) * inv, 0.01f);
        o.w = lrelu((a0.w + a1.w) * inv, 0.01f);
        ((float4*)(out + (size_t)node * ldo))[lane] = o;
    }
}

// ---------------- gated attention combine ----------------
template <int K>
__global__ __launch_bounds__(256) void attn_combine(
    const float* __restrict__ gl, const float* __restrict__ gr,
    const float* __restrict__ v, const float* __restrict__ aW,
    int n,
    float* __restrict__ out1, int ld1,
    float* __restrict__ out2, int ld2, int n2)
{
    int node = blockIdx.x * 2 + (threadIdx.x >> 7);
    int tid = threadIdx.x & 127;
    if (node >= n) return;
    float aw = aW[tid & 15];
    float glv = gl[(size_t)node * 128 + tid];
    float e[K];
    #pragma unroll
    for (int k = 0; k < K; ++k) {
        float z = lrelu(glv + gr[((size_t)node * K + k) * 128 + tid], 0.01f);
        float p = z * aw;
        p += __shfl_xor(p, 1);
        p += __shfl_xor(p, 2);
        p += __shfl_xor(p, 4);
        p += __shfl_xor(p, 8);
        e[k] = p;
    }
    float m = e[0];
    #pragma unroll
    for (int k = 1; k < K; ++k) m = fmaxf(m, e[k]);
    float s = 0.f, w[K];
    #pragma unroll
    for (int k = 0; k < K; ++k) { w[k] = __expf(e[k] - m); s += w[k]; }
    float inv = 1.f / s;
    float acc = 0.f;
    #pragma unroll
    for (int k = 0; k < K; ++k)
        acc += (w[k] * inv) * v[((size_t)node * K + k) * 128 + tid];
    float r = lrelu(acc, 0.01f);
    out1[(size_t)node * ld1 + tid] = r;
    if (out2 && node < n2) out2[(size_t)node * ld2 + tid] = r;
}

// ---------------- final linear 128 -> 2 ----------------
__global__ __launch_bounds__(256) void lin_kernel(
    const float* __restrict__ H, const float* __restrict__ W,
    const float* __restrict__ b, float* __restrict__ out, int n)
{
    int idx = blockIdx.x * 256 + threadIdx.x;
    int node = idx >> 1, c = idx & 1;
    if (node >= n) return;
    float acc = 0.f;
    for (int k = 0; k < 128; ++k)
        acc += H[(size_t)node * 128 + k] * W[k * 2 + c];
    out[(size_t)node * 2 + c] = acc + b[c];
}

extern "C" void kernel_launch(void* const* d_in, const int* in_sizes, int n_in,
                              void* d_out, int out_size, void* d_ws, size_t ws_size,
                              hipStream_t stream)
{
    (void)in_sizes; (void)n_in; (void)out_size; (void)ws_size;
    const float* x       = (const float*)d_in[0];
    const int*   src0    = (const int*)d_in[1];
    const int*   dst0    = (const int*)d_in[2];
    const int*   src1    = (const int*)d_in[3];
    const int*   dst1    = (const int*)d_in[4];
    const float* conv_W  = (const float*)d_in[5];
    const float* conv_al = (const float*)d_in[6];
    const float* conv_ar = (const float*)d_in[7];
    const float* feat_W  = (const float*)d_in[8];
    const float* feat_b  = (const float*)d_in[9];
    const float* relWl_W = (const float*)d_in[10];
    const float* relWl_b = (const float*)d_in[11];
    const float* relWr_W = (const float*)d_in[12];
    const float* relWr_b = (const float*)d_in[13];
    const float* relP_W  = (const float*)d_in[14];
    const float* relP_b  = (const float*)d_in[15];
    const float* rela_W  = (const float*)d_in[16];
    /* d_in[17] rela_b: softmax-invariant */
    const float* proj_W  = (const float*)d_in[18];
    const float* proj_b  = (const float*)d_in[19];
    const float* hopWl_W = (const float*)d_in[20];
    const float* hopWl_b = (const float*)d_in[21];
    const float* hopWr_W = (const float*)d_in[22];
    const float* hopWr_b = (const float*)d_in[23];
    const float* hopP_W  = (const float*)d_in[24];
    const float* hopP_b  = (const float*)d_in[25];
    const float* hopa_W  = (const float*)d_in[26];
    /* d_in[27] hopa_b: softmax-invariant */
    const float* lin_W   = (const float*)d_in[28];
    const float* lin_b   = (const float*)d_in[29];
    float* out = (float*)d_out;

    // ---- static workspace layout (proven 257.2 MB footprint) ----
    char* base = (char*)d_ws;
    size_t off = 0;
    auto alloc = [&](size_t bytes) -> void* {
        void* p = base + off;
        off += (bytes + 255) & ~(size_t)255;
        return p;
    };
    float* hopstack = (float*)alloc((size_t)N2 * 384 * 4);   // (25000, 3, 128)
    float* F        = (float*)alloc((size_t)N1 * 512 * 4);   // stacked feats (n, 4, 128)
    float* glbuf    = (float*)alloc((size_t)N1 * 128 * 4);
    float* h1       = (float*)alloc((size_t)N1 * 128 * 4);
    size_t convBase = off;
    float* P        = (float*)alloc((size_t)N0 * 128 * 4);   // conv projection
    float* el       = (float*)alloc((size_t)N0 * 4 * 4);
    float* er       = (float*)alloc((size_t)N0 * 4 * 4);
    float* eb       = (float*)alloc((size_t)E0 * 4 * 4);
    int*   csr      = (int*)alloc((size_t)E0 * 4);
    int*   counts   = (int*)alloc((size_t)N1 * 4);
    int*   incl     = (int*)alloc((size_t)N1 * 4);
    int*   offs     = (int*)alloc((size_t)(N1 + 1) * 4);
    int*   cursor   = (int*)alloc((size_t)N1 * 4);
    int*   bsum     = (int*)alloc(256 * 4);
    // attention chunk buffers ALIAS the conv region (disjoint lifetimes):
    // grbuf+vbuf = 2*12288*512*4 = 50.3 MB  <  conv region 65.2 MB
    const int CHUNK = 12288;
    float* grbuf = (float*)(base + convBase);
    float* vbuf  = grbuf + (size_t)CHUNK * 512;
    float* hout  = h1;   // h1 dead after layer-1 gl/feat GEMMs

    auto run_conv = [&](const float* h, int n_src, int n_dst,
                        const int* srcJ, const int* dstJ, int E,
                        const float* Wc, const float* al, const float* ar,
                        float* outF) {
        gemm128<<<(n_src + 31) / 32, 256, 0, stream>>>(h, Wc, nullptr, P, 128, n_src, -1.f);
        elr_kernel<<<((unsigned)n_src * 128 + 255) / 256, 256, 0, stream>>>(P, al, ar, el, er, n_src);
        hipMemsetAsync(counts, 0, (size_t)n_dst * sizeof(int), stream);
        count_kernel<<<(E + 255) / 256, 256, 0, stream>>>(dstJ, counts, E);
        int nb = (n_dst + 1023) / 1024;
        scan_block_kernel<<<nb, 1024, 0, stream>>>(counts, incl, bsum, n_dst);
        scan_bsum_kernel<<<1, 64, 0, stream>>>(bsum, nb);
        scan_final_kernel<<<(n_dst + 255) / 256, 256, 0, stream>>>(counts, incl, bsum, offs, cursor, n_dst, nb);
        scatter_kernel<<<(E + 255) / 256, 256, 0, stream>>>(dstJ, cursor, csr, E);
        edge_e_kernel<<<(E + 255) / 256, 256, 0, stream>>>(srcJ, dstJ, el, er, eb, E);
        gat_gather2<<<n_dst, 256, 0, stream>>>(srcJ, csr, offs, eb, P, outF, 512, n_dst);
    };

    auto run_attn = [&](const float* prev, const float* feats, int n, int K,
                        const float* Wl, const float* bl,
                        const float* Wr, const float* br,
                        const float* Wp, const float* bp,
                        const float* aW,
                        float* out1, int ld1, float* out2, int ld2, int n2) {
        gemm128<<<(n + 31) / 32, 256, 0, stream>>>(prev, Wl, bl, glbuf, 128, n, -1.f);
        for (int c = 0; c < n; c += CHUNK) {
            int mn = (n - c < CHUNK) ? (n - c) : CHUNK;
            int rows = mn * K;
            const float* Xf = feats + (size_t)c * K * 128;
            gemm128<<<(rows + 31) / 32, 256, 0, stream>>>(Xf, Wr, br, grbuf, 128, rows, -1.f);
            gemm128<<<(rows + 31) / 32, 256, 0, stream>>>(Xf, Wp, bp, vbuf, 128, rows, -1.f);
            float* o2 = nullptr;
            int o2n = 0;
            if (out2 && c < n2) {
                o2 = out2 + (size_t)c * ld2;
                o2n = ((n2 - c) < mn) ? (n2 - c) : mn;
            }
            if (K == 4)
                attn_combine<4><<<(mn + 1) / 2, 256, 0, stream>>>(
                    glbuf + (size_t)c * 128, grbuf, vbuf, aW, mn,
                    out1 + (size_t)c * ld1, ld1, o2, ld2, o2n);
            else
                attn_combine<3><<<(mn + 1) / 2, 256, 0, stream>>>(
                    glbuf + (size_t)c * 128, grbuf, vbuf, aW, mn,
                    out1 + (size_t)c * ld1, ld1, o2, ld2, o2n);
        }
    };

    // ---- layer_features[0] ----
    gemm128<<<(N2 + 31) / 32, 256, 0, stream>>>(x, proj_W, proj_b, hopstack, 384, N2, -1.f);

    // ---- layer 0 ----
    for (int j = 0; j < 3; ++j)
        run_conv(x, N0, N1, src0 + (size_t)j * E0, dst0 + (size_t)j * E0, E0,
                 conv_W + (size_t)j * 16384, conv_al + (size_t)j * 128, conv_ar + (size_t)j * 128,
                 F + j * 128);
    gemm128<<<(N1 + 31) / 32, 256, 0, stream>>>(x, feat_W, feat_b, F + 3 * 128, 512, N1, 0.01f);
    run_attn(x, F, N1, 4,
             relWl_W, relWl_b, relWr_W, relWr_b, relP_W, relP_b, rela_W,
             h1, 128, hopstack + 128, 384, N2);

    // ---- layer 1 ----
    for (int j = 0; j < 3; ++j)
        run_conv(h1, N1, N2, src1 + (size_t)j * E1, dst1 + (size_t)j * E1, E1,
                 conv_W + (size_t)(3 + j) * 16384, conv_al + (size_t)(3 + j) * 128,
                 conv_ar + (size_t)(3 + j) * 128, F + j * 128);
    gemm128<<<(N2 + 31) / 32, 256, 0, stream>>>(h1, feat_W + 16384, feat_b + 128, F + 3 * 128, 512, N2, 0.01f);
    run_attn(h1, F, N2, 4,
             relWl_W + 16384, relWl_b + 128, relWr_W + 16384, relWr_b + 128,
             relP_W + 16384, relP_b + 128, rela_W + 16,
             hopstack + 2 * 128, 384, nullptr, 0, 0);

    // ---- hop attention ----
    run_attn(x, hopstack, N2, 3,
             hopWl_W, hopWl_b, hopWr_W, hopWr_b, hopP_W, hopP_b, hopa_W,
             hout, 128, nullptr, 0, 0);

    // ---- final linear ----
    lin_kernel<<<(N2 * 2 + 255) / 256, 256, 0, stream>>>(hout, lin_W, lin_b, out, N2);
}

// Round 3
// 1613.278 us; speedup vs baseline: 1.7595x; 1.3687x over previous
//
#include <hip/hip_runtime.h>

#define N0 100000
#define N1 50000
#define N2 25000
#define E0 500000
#define E1 250000
#define N_TOT (3 * N1 + 3 * N2)       // 225000 CSR node slots (6 reps)
#define NE_ALL (3 * E0 + 3 * E1)      // 2.25M edges total
#define NB_SCAN ((N_TOT + 1023) / 1024)

static __device__ __forceinline__ float lrelu(float x, float s) {
    return x >= 0.f ? x : s * x;
}

// ---- GEMM: Y = act(X @ W + b); optional fused el/er head-reductions ----
__global__ __launch_bounds__(256) void gemm128(
    const float* __restrict__ X,
    const float* __restrict__ W,
    const float* __restrict__ bias,
    float* __restrict__ Y, int ldy,
    int M, float slope,
    const float* __restrict__ al, const float* __restrict__ ar,
    float* __restrict__ el, float* __restrict__ er)
{
    __shared__ float xs[32][128];
    const int row0 = blockIdx.x * 32;
    const int tid = threadIdx.x;
    for (int i = tid; i < 32 * 32; i += 256) {
        int r = i >> 5, c4 = i & 31;
        float4 v = make_float4(0.f, 0.f, 0.f, 0.f);
        if (row0 + r < M) v = ((const float4*)(X + (size_t)(row0 + r) * 128))[c4];
        ((float4*)&xs[r][0])[c4] = v;
    }
    __syncthreads();
    const int row_t = tid >> 5;
    const int col_t = tid & 31;
    float acc[4][4] = {};
    #pragma unroll 4
    for (int k4 = 0; k4 < 32; ++k4) {
        const float4* Wp = (const float4*)(W + (size_t)k4 * 4 * 128);
        float4 w0 = Wp[col_t];
        float4 w1 = Wp[32 + col_t];
        float4 w2 = Wp[64 + col_t];
        float4 w3 = Wp[96 + col_t];
        #pragma unroll
        for (int r = 0; r < 4; ++r) {
            float4 xv = ((const float4*)&xs[row_t * 4 + r][0])[k4];
            acc[r][0] += xv.x * w0.x + xv.y * w1.x + xv.z * w2.x + xv.w * w3.x;
            acc[r][1] += xv.x * w0.y + xv.y * w1.y + xv.z * w2.y + xv.w * w3.y;
            acc[r][2] += xv.x * w0.z + xv.y * w1.z + xv.z * w2.z + xv.w * w3.z;
            acc[r][3] += xv.x * w0.w + xv.y * w1.w + xv.z * w2.w + xv.w * w3.w;
        }
    }
    #pragma unroll
    for (int r = 0; r < 4; ++r) {
        int row = row0 + row_t * 4 + r;
        if (row >= M) continue;
        float4 o;
        float* op = (float*)&o;
        #pragma unroll
        for (int c = 0; c < 4; ++c) {
            float vv = acc[r][c];
            if (bias) vv += bias[col_t * 4 + c];
            if (slope >= 0.f) vv = lrelu(vv, slope);
            op[c] = vv;
        }
        *((float4*)(Y + (size_t)row * ldy + col_t * 4)) = o;
    }
    if (al) {  // fused el/er: head g = col>>5 = col_t>>3; 8-lane shuffle reduce
        float4 al4 = ((const float4*)al)[col_t];
        float4 ar4 = ((const float4*)ar)[col_t];
        #pragma unroll
        for (int r = 0; r < 4; ++r) {
            float elp = acc[r][0] * al4.x + acc[r][1] * al4.y + acc[r][2] * al4.z + acc[r][3] * al4.w;
            float erp = acc[r][0] * ar4.x + acc[r][1] * ar4.y + acc[r][2] * ar4.z + acc[r][3] * ar4.w;
            elp += __shfl_xor(elp, 1); erp += __shfl_xor(erp, 1);
            elp += __shfl_xor(elp, 2); erp += __shfl_xor(erp, 2);
            elp += __shfl_xor(elp, 4); erp += __shfl_xor(erp, 4);
            if ((col_t & 7) == 0) {
                int row = row0 + row_t * 4 + r;
                if (row < M) {
                    int g = col_t >> 3;
                    el[(size_t)row * 4 + g] = elp;
                    er[(size_t)row * 4 + g] = erp;
                }
            }
        }
    }
}

// ---------------- batched CSR build over all 6 (layer,rep) graphs ----------
__global__ __launch_bounds__(256) void count_all(
    const int* __restrict__ dst0, const int* __restrict__ dst1, int* __restrict__ counts)
{
    int idx = blockIdx.x * 256 + threadIdx.x;
    if (idx < 3 * E0) {
        atomicAdd(&counts[(idx / E0) * N1 + dst0[idx]], 1);
    } else {
        int k = idx - 3 * E0;
        if (k < 3 * E1) atomicAdd(&counts[3 * N1 + (k / E1) * N2 + dst1[k]], 1);
    }
}

__global__ __launch_bounds__(1024) void scan_block_kernel(
    const int* __restrict__ counts, int* __restrict__ incl, int* __restrict__ bsum, int n)
{
    __shared__ int s[1024];
    int i = blockIdx.x * 1024 + threadIdx.x;
    int v = (i < n) ? counts[i] : 0;
    s[threadIdx.x] = v;
    __syncthreads();
    for (int off = 1; off < 1024; off <<= 1) {
        int t = (threadIdx.x >= off) ? s[threadIdx.x - off] : 0;
        __syncthreads();
        s[threadIdx.x] += t;
        __syncthreads();
    }
    if (i < n) incl[i] = s[threadIdx.x];
    if (threadIdx.x == 1023) bsum[blockIdx.x] = s[1023];
}

__global__ __launch_bounds__(256) void scan_bsum_block(int* bsum, int nb)
{
    __shared__ int s[256];
    int t = threadIdx.x;
    int v = (t < nb) ? bsum[t] : 0;
    s[t] = v;
    __syncthreads();
    for (int off = 1; off < 256; off <<= 1) {
        int tv = (t >= off) ? s[t - off] : 0;
        __syncthreads();
        s[t] += tv;
        __syncthreads();
    }
    if (t < nb) bsum[t] = s[t] - v;        // exclusive
    if (t == nb - 1) bsum[nb] = s[t];      // grand total
}

__global__ __launch_bounds__(256) void scan_final_kernel(
    const int* __restrict__ counts, const int* __restrict__ incl,
    const int* __restrict__ bsum, int* __restrict__ offs, int* __restrict__ cursor,
    int n, int nb)
{
    int i = blockIdx.x * 256 + threadIdx.x;
    if (i < n) {
        int ex = incl[i] - counts[i] + bsum[i >> 10];
        offs[i] = ex;
        cursor[i] = ex;
    }
    if (i == 0) offs[n] = bsum[nb];
}

__global__ __launch_bounds__(256) void scatter_all(
    const int* __restrict__ dst0, const int* __restrict__ dst1,
    int* __restrict__ cursor, int* __restrict__ csr)
{
    int idx = blockIdx.x * 256 + threadIdx.x;
    if (idx < 3 * E0) {
        int rep = idx / E0, e = idx - rep * E0;
        int p = atomicAdd(&cursor[rep * N1 + dst0[idx]], 1);
        csr[p] = e;
    } else {
        int k = idx - 3 * E0;
        if (k < 3 * E1) {
            int rep = k / E1, e = k - rep * E1;
            int p = atomicAdd(&cursor[3 * N1 + rep * N2 + dst1[k]], 1);
            csr[p] = e;
        }
    }
}

// ---- single-pass softmax gather (no max; |e|<~1 so exp is safe/exact) ----
// 256 threads: slot = t>>5 (8 edges in flight), lane = t&31 (float4), g = lane>>3
__global__ __launch_bounds__(256) void gat_gather3(
    const int* __restrict__ src, const int* __restrict__ csr,
    const int* __restrict__ offs, int nodeBase,
    const float* __restrict__ el, const float* __restrict__ er,
    const float* __restrict__ P, float* __restrict__ out, int ldo)
{
    __shared__ float4 accs[8][32];
    __shared__ float reds[8][32];
    int node = blockIdx.x;
    int t = threadIdx.x;
    int lane = t & 31;
    int slot = t >> 5;
    int g = lane >> 3;
    int beg = offs[nodeBase + node], end = offs[nodeBase + node + 1];
    float erg = er[(size_t)node * 4 + g];
    float den = 0.f;
    float4 acc = make_float4(0.f, 0.f, 0.f, 0.f);
    for (int i = beg + slot; i < end; i += 8) {
        int e = csr[i];
        int s = src[e];
        float w = __expf(lrelu(el[(size_t)s * 4 + g] + erg, 0.2f));
        float4 p = ((const float4*)(P + (size_t)s * 128))[lane];
        den += w;
        acc.x += w * p.x; acc.y += w * p.y; acc.z += w * p.z; acc.w += w * p.w;
    }
    reds[slot][lane] = den;
    accs[slot][lane] = acc;
    __syncthreads();
    if (slot < 4) {
        reds[slot][lane] += reds[slot + 4][lane];
        float4 b = accs[slot + 4][lane];
        accs[slot][lane].x += b.x; accs[slot][lane].y += b.y;
        accs[slot][lane].z += b.z; accs[slot][lane].w += b.w;
    }
    __syncthreads();
    if (slot < 2) {
        reds[slot][lane] += reds[slot + 2][lane];
        float4 b = accs[slot + 2][lane];
        accs[slot][lane].x += b.x; accs[slot][lane].y += b.y;
        accs[slot][lane].z += b.z; accs[slot][lane].w += b.w;
    }
    __syncthreads();
    if (slot == 0) {
        float d = reds[0][lane] + reds[1][lane];
        float4 a0 = accs[0][lane], a1 = accs[1][lane];
        float inv = (end > beg) ? 1.f / d : 0.f;
        float4 o;
        o.x = lrelu((a0.x + a1.x) * inv, 0.01f);
        o.y = lrelu((a0.y + a1.y) * inv, 0.01f);
        o.z = lrelu((a0.z + a1.z) * inv, 0.01f);
        o.w = lrelu((a0.w + a1.w) * inv, 0.01f);
        ((float4*)(out + (size_t)node * ldo))[lane] = o;
    }
}

// ---- fused gated attention: gr-GEMM + v-GEMM + softmax combine ----
// Block: NODES nodes (ROWS=K*NODES<=32 feat rows). gr/v live only in LDS.
template <int K, int NODES>
__global__ __launch_bounds__(256) void attn_fused(
    const float* __restrict__ feats, const float* __restrict__ gl,
    const float* __restrict__ Wr, const float* __restrict__ br,
    const float* __restrict__ Wp, const float* __restrict__ bp,
    const float* __restrict__ aW, int n,
    float* __restrict__ out1, int ld1,
    float* __restrict__ out2, int ld2, int n2)
{
    constexpr int ROWS = K * NODES;
    __shared__ float xs[32][128];   // feat tile, then reused for gr
    __shared__ float vs[32][128];
    const int node0 = blockIdx.x * NODES;
    const int row0 = node0 * K;
    const int totalrows = n * K;
    const int tid = threadIdx.x;
    for (int i = tid; i < 32 * 32; i += 256) {
        int r = i >> 5, c4 = i & 31;
        float4 v = make_float4(0.f, 0.f, 0.f, 0.f);
        if (r < ROWS && row0 + r < totalrows)
            v = ((const float4*)(feats + (size_t)(row0 + r) * 128))[c4];
        ((float4*)&xs[r][0])[c4] = v;
    }
    __syncthreads();
    const int row_t = tid >> 5;
    const int col_t = tid & 31;
    float aG[4][4] = {}, aV[4][4] = {};
    #pragma unroll 2
    for (int k4 = 0; k4 < 32; ++k4) {
        const float4* Wrp = (const float4*)(Wr + (size_t)k4 * 4 * 128);
        const float4* Wpp = (const float4*)(Wp + (size_t)k4 * 4 * 128);
        float4 r0 = Wrp[col_t], r1 = Wrp[32 + col_t], r2 = Wrp[64 + col_t], r3 = Wrp[96 + col_t];
        float4 p0 = Wpp[col_t], p1 = Wpp[32 + col_t], p2 = Wpp[64 + col_t], p3 = Wpp[96 + col_t];
        #pragma unroll
        for (int r = 0; r < 4; ++r) {
            float4 xv = ((const float4*)&xs[row_t * 4 + r][0])[k4];
            aG[r][0] += xv.x * r0.x + xv.y * r1.x + xv.z * r2.x + xv.w * r3.x;
            aG[r][1] += xv.x * r0.y + xv.y * r1.y + xv.z * r2.y + xv.w * r3.y;
            aG[r][2] += xv.x * r0.z + xv.y * r1.z + xv.z * r2.z + xv.w * r3.z;
            aG[r][3] += xv.x * r0.w + xv.y * r1.w + xv.z * r2.w + xv.w * r3.w;
            aV[r][0] += xv.x * p0.x + xv.y * p1.x + xv.z * p2.x + xv.w * p3.x;
            aV[r][1] += xv.x * p0.y + xv.y * p1.y + xv.z * p2.y + xv.w * p3.y;
            aV[r][2] += xv.x * p0.z + xv.y * p1.z + xv.z * p2.z + xv.w * p3.z;
            aV[r][3] += xv.x * p0.w + xv.y * p1.w + xv.z * p2.w + xv.w * p3.w;
        }
    }
    __syncthreads();   // all xs reads done; safe to overwrite with gr
    float4 br4 = ((const float4*)br)[col_t];
    float4 bp4 = ((const float4*)bp)[col_t];
    #pragma unroll
    for (int r = 0; r < 4; ++r) {
        int row = row_t * 4 + r;
        ((float4*)&xs[row][0])[col_t] = make_float4(aG[r][0] + br4.x, aG[r][1] + br4.y,
                                                    aG[r][2] + br4.z, aG[r][3] + br4.w);
        ((float4*)&vs[row][0])[col_t] = make_float4(aV[r][0] + bp4.x, aV[r][1] + bp4.y,
                                                    aV[r][2] + bp4.z, aV[r][3] + bp4.w);
    }
    __syncthreads();
    // combine: lane covers dims lane*4..+3; head a = lane>>2 (16 dims = 4 lanes)
    const int lane = tid & 31;
    float4 aw4 = ((const float4*)aW)[lane & 3];
    for (int j = tid >> 5; j < NODES; j += 8) {
        int node = node0 + j;
        if (node >= n) continue;
        float4 gl4 = ((const float4*)(gl + (size_t)node * 128))[lane];
        float e[K];
        #pragma unroll
        for (int k = 0; k < K; ++k) {
            float4 g4 = ((const float4*)&xs[j * K + k][0])[lane];
            float zx = lrelu(gl4.x + g4.x, 0.01f);
            float zy = lrelu(gl4.y + g4.y, 0.01f);
            float zz = lrelu(gl4.z + g4.z, 0.01f);
            float zw = lrelu(gl4.w + g4.w, 0.01f);
            float p = zx * aw4.x + zy * aw4.y + zz * aw4.z + zw * aw4.w;
            p += __shfl_xor(p, 1);
            p += __shfl_xor(p, 2);
            e[k] = p;
        }
        float m = e[0];
        #pragma unroll
        for (int k = 1; k < K; ++k) m = fmaxf(m, e[k]);
        float s = 0.f, w[K];
        #pragma unroll
        for (int k = 0; k < K; ++k) { w[k] = __expf(e[k] - m); s += w[k]; }
        float inv = 1.f / s;
        float4 o = make_float4(0.f, 0.f, 0.f, 0.f);
        #pragma unroll
        for (int k = 0; k < K; ++k) {
            float wk = w[k] * inv;
            float4 v4 = ((const float4*)&vs[j * K + k][0])[lane];
            o.x += wk * v4.x; o.y += wk * v4.y; o.z += wk * v4.z; o.w += wk * v4.w;
        }
        o.x = lrelu(o.x, 0.01f); o.y = lrelu(o.y, 0.01f);
        o.z = lrelu(o.z, 0.01f); o.w = lrelu(o.w, 0.01f);
        ((float4*)(out1 + (size_t)node * ld1))[lane] = o;
        if (out2 && node < n2) ((float4*)(out2 + (size_t)node * ld2))[lane] = o;
    }
}

// ---------------- final linear 128 -> 2 ----------------
__global__ __launch_bounds__(256) void lin_kernel(
    const float* __restrict__ H, const float* __restrict__ W,
    const float* __restrict__ b, float* __restrict__ out, int n)
{
    int idx = blockIdx.x * 256 + threadIdx.x;
    int node = idx >> 1, c = idx & 1;
    if (node >= n) return;
    float acc = 0.f;
    for (int k = 0; k < 128; ++k)
        acc += H[(size_t)node * 128 + k] * W[k * 2 + c];
    out[(size_t)node * 2 + c] = acc + b[c];
}

extern "C" void kernel_launch(void* const* d_in, const int* in_sizes, int n_in,
                              void* d_out, int out_size, void* d_ws, size_t ws_size,
                              hipStream_t stream)
{
    (void)in_sizes; (void)n_in; (void)out_size; (void)ws_size;
    const float* x       = (const float*)d_in[0];
    const int*   src0    = (const int*)d_in[1];
    const int*   dst0    = (const int*)d_in[2];
    const int*   src1    = (const int*)d_in[3];
    const int*   dst1    = (const int*)d_in[4];
    const float* conv_W  = (const float*)d_in[5];
    const float* conv_al = (const float*)d_in[6];
    const float* conv_ar = (const float*)d_in[7];
    const float* feat_W  = (const float*)d_in[8];
    const float* feat_b  = (const float*)d_in[9];
    const float* relWl_W = (const float*)d_in[10];
    const float* relWl_b = (const float*)d_in[11];
    const float* relWr_W = (const float*)d_in[12];
    const float* relWr_b = (const float*)d_in[13];
    const float* relP_W  = (const float*)d_in[14];
    const float* relP_b  = (const float*)d_in[15];
    const float* rela_W  = (const float*)d_in[16];
    /* d_in[17] rela_b: softmax-invariant */
    const float* proj_W  = (const float*)d_in[18];
    const float* proj_b  = (const float*)d_in[19];
    const float* hopWl_W = (const float*)d_in[20];
    const float* hopWl_b = (const float*)d_in[21];
    const float* hopWr_W = (const float*)d_in[22];
    const float* hopWr_b = (const float*)d_in[23];
    const float* hopP_W  = (const float*)d_in[24];
    const float* hopP_b  = (const float*)d_in[25];
    const float* hopa_W  = (const float*)d_in[26];
    /* d_in[27] hopa_b: softmax-invariant */
    const float* lin_W   = (const float*)d_in[28];
    const float* lin_b   = (const float*)d_in[29];
    float* out = (float*)d_out;

    // ---- workspace layout (256.3 MB, under proven 257.2 MB) ----
    char* base = (char*)d_ws;
    size_t off = 0;
    auto alloc = [&](size_t bytes) -> void* {
        void* p = base + off;
        off += (bytes + 255) & ~(size_t)255;
        return p;
    };
    float* hopstack = (float*)alloc((size_t)N2 * 384 * 4);   // (25000, 3, 128)
    float* F        = (float*)alloc((size_t)N1 * 512 * 4);   // stacked feats (n, 4, 128)
    float* glbuf    = (float*)alloc((size_t)N1 * 128 * 4);
    float* h1       = (float*)alloc((size_t)N1 * 128 * 4);
    float* P        = (float*)alloc((size_t)N0 * 128 * 4);
    float* el       = (float*)alloc((size_t)N0 * 4 * 4);
    float* er       = (float*)alloc((size_t)N0 * 4 * 4);
    int*   csr_all  = (int*)alloc((size_t)NE_ALL * 4);
    int*   offs     = (int*)alloc((size_t)(N_TOT + 1) * 4);
    int*   bsum     = (int*)alloc(512 * 4);
    // CSR-build temporaries alias glbuf (2.7 MB << 25.6 MB; disjoint lifetime)
    int* counts = (int*)glbuf;
    int* incl   = counts + N_TOT;
    int* cursor = incl + N_TOT;
    float* hout = h1;   // h1 dead by the hop stage

    // ---- batched CSR build for all 6 (layer,rep) graphs ----
    hipMemsetAsync(counts, 0, (size_t)N_TOT * 4, stream);
    count_all<<<(NE_ALL + 255) / 256, 256, 0, stream>>>(dst0, dst1, counts);
    scan_block_kernel<<<NB_SCAN, 1024, 0, stream>>>(counts, incl, bsum, N_TOT);
    scan_bsum_block<<<1, 256, 0, stream>>>(bsum, NB_SCAN);
    scan_final_kernel<<<(N_TOT + 255) / 256, 256, 0, stream>>>(counts, incl, bsum, offs, cursor, N_TOT, NB_SCAN);
    scatter_all<<<(NE_ALL + 255) / 256, 256, 0, stream>>>(dst0, dst1, cursor, csr_all);

    // ---- layer_features[0] = x[:N2] @ proj_W + proj_b ----
    gemm128<<<(N2 + 31) / 32, 256, 0, stream>>>(x, proj_W, proj_b, hopstack, 384, N2, -1.f,
                                                nullptr, nullptr, nullptr, nullptr);

    // ---- layer 0 convs ----
    for (int j = 0; j < 3; ++j) {
        gemm128<<<(N0 + 31) / 32, 256, 0, stream>>>(
            x, conv_W + (size_t)j * 16384, nullptr, P, 128, N0, -1.f,
            conv_al + (size_t)j * 128, conv_ar + (size_t)j * 128, el, er);
        gat_gather3<<<N1, 256, 0, stream>>>(src0 + (size_t)j * E0, csr_all, offs, j * N1,
                                            el, er, P, F + j * 128, 512);
    }
    gemm128<<<(N1 + 31) / 32, 256, 0, stream>>>(x, feat_W, feat_b, F + 3 * 128, 512, N1, 0.01f,
                                                nullptr, nullptr, nullptr, nullptr);
    // ---- layer 0 attention ----
    gemm128<<<(N1 + 31) / 32, 256, 0, stream>>>(x, relWl_W, relWl_b, glbuf, 128, N1, -1.f,
                                                nullptr, nullptr, nullptr, nullptr);
    attn_fused<4, 8><<<(N1 + 7) / 8, 256, 0, stream>>>(
        F, glbuf, relWr_W, relWr_b, relP_W, relP_b, rela_W, N1,
        h1, 128, hopstack + 128, 384, N2);

    // ---- layer 1 convs ----
    for (int j = 0; j < 3; ++j) {
        gemm128<<<(N1 + 31) / 32, 256, 0, stream>>>(
            h1, conv_W + (size_t)(3 + j) * 16384, nullptr, P, 128, N1, -1.f,
            conv_al + (size_t)(3 + j) * 128, conv_ar + (size_t)(3 + j) * 128, el, er);
        gat_gather3<<<N2, 256, 0, stream>>>(src1 + (size_t)j * E1, csr_all, offs, 3 * N1 + j * N2,
                                            el, er, P, F + j * 128, 512);
    }
    gemm128<<<(N2 + 31) / 32, 256, 0, stream>>>(h1, feat_W + 16384, feat_b + 128, F + 3 * 128, 512, N2, 0.01f,
                                                nullptr, nullptr, nullptr, nullptr);
    // ---- layer 1 attention ----
    gemm128<<<(N2 + 31) / 32, 256, 0, stream>>>(h1, relWl_W + 16384, relWl_b + 128, glbuf, 128, N2, -1.f,
                                                nullptr, nullptr, nullptr, nullptr);
    attn_fused<4, 8><<<(N2 + 7) / 8, 256, 0, stream>>>(
        F, glbuf, relWr_W + 16384, relWr_b + 128, relP_W + 16384, relP_b + 128, rela_W + 16, N2,
        hopstack + 2 * 128, 384, nullptr, 0, 0);

    // ---- hop attention over [proj, h1[:N2], h2] ----
    gemm128<<<(N2 + 31) / 32, 256, 0, stream>>>(x, hopWl_W, hopWl_b, glbuf, 128, N2, -1.f,
                                                nullptr, nullptr, nullptr, nullptr);
    attn_fused<3, 10><<<(N2 + 9) / 10, 256, 0, stream>>>(
        hopstack, glbuf, hopWr_W, hopWr_b, hopP_W, hopP_b, hopa_W, N2,
        hout, 128, nullptr, 0, 0);

    // ---- final linear ----
    lin_kernel<<<(N2 * 2 + 255) / 256, 256, 0, stream>>>(hout, lin_W, lin_b, out, N2);
}